// Round 3
// 829.989 us; speedup vs baseline: 1.3027x; 1.3027x over previous
//
#include <hip/hip_runtime.h>

// RBFNSemanticLayer, MI355X (gfx950) — R6: resubmit of R4/R5.
// Two prior submissions failed at the container/broker level (no compile
// error, no counters, "container failed twice"). Source re-audited: all
// accesses in-bounds, no new API surface vs the harness-verified R3,
// compile-time trip counts only. No kernel-level evidence to revise on.
//
// B=64, P=2048, K=16, DIM=3, NC=16, SFD=64, OUTF=64
//
// Diagnosis of R3: rbfn_compute_kernel spilled (VGPR=256 cap, occupancy
// 1 block/CU, 620 MB of scratch writes vs 33 MB logical) because the
// fully-unrolled 4-pass loop hoisted ~208 VGPRs of global loads.
// Fix: #pragma unroll 1 on the pass loop, and fuse the spatial k-reduce
// (old kernel 1) inline — one kernel, minimal traffic:
//   read spatial 537 MB + features 25 MB, write out 33.5 MB ≈ 596 MB.
//
// Layout per block: 256 threads = 16 groups of 16 lanes; group handles one
// p per pass (4 passes, P_PER_BLOCK=64). Lane t in a group owns RBF center
// t and output chunk o=[4t..4t+3].

#define PP 2048
#define KK 16
#define NC 16
#define SFDIM 64
#define OUTF 64
#define THREADS 256
#define P_PER_BLOCK 64

__global__ __launch_bounds__(THREADS)
void rbfn_fused_kernel(const float* __restrict__ features,
                       const float4* __restrict__ spatial,   // (B,P,K,SFD) as float4
                       const float* __restrict__ centers,
                       const float* __restrict__ rbfw,
                       const float* __restrict__ w,
                       float4* __restrict__ out)              // (B,P,OUTF) as float4
{
    __shared__ float4 lds_w4[SFDIM * OUTF / 4];   // 16 KB: w[b] row-major (s, o)
    __shared__ float4 lds_wr4[NC * SFDIM / 4];    // 4 KB:  rbfw (c, s)

    const int tid = threadIdx.x;
    const int b = blockIdx.y;
    const int p0 = blockIdx.x * P_PER_BLOCK;

    const float4* wg4 = (const float4*)(w + (size_t)b * SFDIM * OUTF);
    #pragma unroll
    for (int i = 0; i < 4; ++i)
        lds_w4[tid + i * THREADS] = wg4[tid + i * THREADS];
    lds_wr4[tid] = ((const float4*)rbfw)[tid];
    __syncthreads();

    const int t = tid & 15;        // o4-chunk index / rbf-center index
    const int base = tid & 48;     // 16-lane group base within the wave

    const float C0 = centers[t];
    const float C1 = centers[NC + t];
    const float C2 = centers[2 * NC + t];

    // NOTE: unroll 1 is the spill fix — do NOT fully unroll this loop.
    #pragma unroll 1
    for (int pass = 0; pass < P_PER_BLOCK / 16; ++pass) {
        const int p = p0 + pass * 16 + (tid >> 4);
        const size_t bp = (size_t)b * PP + p;

        // ---- spatial k-reduction, fused (was kernel 1) -------------------
        // Row for bp is K*SFD = 1024 floats = 256 float4; this lane reads
        // its s-chunk t at offsets t, t+16, ..., t+240. Same 4-chain
        // accumulation order as the previous 2-kernel version (bitwise
        // identical numerics).
        const float4* sp4 = spatial + bp * (KK * SFDIM / 4) + t;
        float4 a0 = sp4[0 * 16], a1 = sp4[1 * 16], a2 = sp4[2 * 16], a3 = sp4[3 * 16];
        #pragma unroll
        for (int k = 4; k < KK; k += 4) {
            float4 v0 = sp4[(k + 0) * 16];
            float4 v1 = sp4[(k + 1) * 16];
            float4 v2 = sp4[(k + 2) * 16];
            float4 v3 = sp4[(k + 3) * 16];
            a0.x += v0.x; a0.y += v0.y; a0.z += v0.z; a0.w += v0.w;
            a1.x += v1.x; a1.y += v1.y; a1.z += v1.z; a1.w += v1.w;
            a2.x += v2.x; a2.y += v2.y; a2.z += v2.z; a2.w += v2.w;
            a3.x += v3.x; a3.y += v3.y; a3.z += v3.z; a3.w += v3.w;
        }
        float4 sp;
        sp.x = (a0.x + a1.x) + (a2.x + a3.x);
        sp.y = (a0.y + a1.y) + (a2.y + a3.y);
        sp.z = (a0.z + a1.z) + (a2.z + a3.z);
        sp.w = (a0.w + a1.w) + (a2.w + a3.w);

        // ---- RBF sum for this lane's center c = t ------------------------
        const float4* f4 = (const float4*)features + bp * 12;
        float rbfsum = 0.f;
        #define RBF_STEP(FX,FY,FZ) { \
            float dx=(FX)-C0, dy=(FY)-C1, dz=(FZ)-C2; \
            float dn2 = dx*dx + dy*dy + dz*dz; \
            rbfsum += __expf(dn2 * -12.5f); }
        #pragma unroll
        for (int kq = 0; kq < 4; ++kq) {
            float4 a  = f4[kq * 3 + 0];
            float4 bq = f4[kq * 3 + 1];
            float4 cq = f4[kq * 3 + 2];
            RBF_STEP(a.x,  a.y,  a.z);
            RBF_STEP(a.w,  bq.x, bq.y);
            RBF_STEP(bq.z, bq.w, cq.x);
            RBF_STEP(cq.y, cq.z, cq.w);
        }
        #undef RBF_STEP

        // ---- fl4 = sum_c rbfsum[c] * Wr[c, 4t..4t+3] ---------------------
        float4 fl; fl.x = fl.y = fl.z = fl.w = 0.f;
        #pragma unroll
        for (int c = 0; c < NC; ++c) {
            float rs = __shfl(rbfsum, base | c, 64);
            float4 wr = lds_wr4[c * 16 + t];
            fl.x += rs * wr.x; fl.y += rs * wr.y;
            fl.z += rs * wr.z; fl.w += rs * wr.w;
        }

        // ---- x = fl * sp -------------------------------------------------
        float4 x;
        x.x = fl.x * sp.x; x.y = fl.y * sp.y;
        x.z = fl.z * sp.z; x.w = fl.w * sp.w;

        // ---- o4 = sum_s x[s] * w[b, s, 4t..4t+3] -------------------------
        float4 o4; o4.x = o4.y = o4.z = o4.w = 0.f;
        #pragma unroll
        for (int sc = 0; sc < 16; ++sc) {
            float xs0 = __shfl(x.x, base | sc, 64);
            float xs1 = __shfl(x.y, base | sc, 64);
            float xs2 = __shfl(x.z, base | sc, 64);
            float xs3 = __shfl(x.w, base | sc, 64);
            float4 w0 = lds_w4[(sc * 4 + 0) * 16 + t];
            float4 w1 = lds_w4[(sc * 4 + 1) * 16 + t];
            float4 w2 = lds_w4[(sc * 4 + 2) * 16 + t];
            float4 w3 = lds_w4[(sc * 4 + 3) * 16 + t];
            o4.x += xs0 * w0.x + xs1 * w1.x + xs2 * w2.x + xs3 * w3.x;
            o4.y += xs0 * w0.y + xs1 * w1.y + xs2 * w2.y + xs3 * w3.y;
            o4.z += xs0 * w0.z + xs1 * w1.z + xs2 * w2.z + xs3 * w3.z;
            o4.w += xs0 * w0.w + xs1 * w1.w + xs2 * w2.w + xs3 * w3.w;
        }

        out[bp * 16 + t] = o4;
    }
}

extern "C" void kernel_launch(void* const* d_in, const int* in_sizes, int n_in,
                              void* d_out, int out_size, void* d_ws, size_t ws_size,
                              hipStream_t stream) {
    const float* features = (const float*)d_in[0];
    const float* spatial  = (const float*)d_in[1];
    const float* centers  = (const float*)d_in[2];
    const float* rbfw     = (const float*)d_in[3];
    const float* w        = (const float*)d_in[4];

    dim3 grid(PP / P_PER_BLOCK, 64);
    rbfn_fused_kernel<<<grid, THREADS, 0, stream>>>(
        features, (const float4*)spatial, centers, rbfw, w, (float4*)d_out);
}

// Round 4
// 719.758 us; speedup vs baseline: 1.5022x; 1.1532x over previous
//
#include <hip/hip_runtime.h>

// RBFNSemanticLayer, MI355X (gfx950) — R7: phase-split fused kernel.
// B=64, P=2048, K=16, DIM=3, NC=16, SFD=64, OUTF=64
//
// R6 post-mortem: fused kernel ran at only ~2.5-3.5 TB/s effective (harness
// fills on the same run stream at 6.4 TB/s). Cause: per-pass structure
// {16 loads -> ~1400cy VALU tail} with all resident waves phase-locked ->
// CU has long windows with zero outstanding VMEM (BW duty ~40-55%).
//
// Fix: Phase A does ALL 4 passes' spatial k-reductions as one contiguous
// 64-load stream (same per-pass 4-chain summation tree as R6 -> identical
// numerics), yielding sp[0..3]. Then 4 per-pass compute tails, separated by
// sched_barrier(0) so the compiler can't hoist all feature loads at once
// (the R3 spill failure mode). Traffic unchanged (~565 MB read, 33.5 MB
// write); this is purely a memory-duty-cycle fix.
//
// Layout per block: 256 threads = 16 groups of 16 lanes; group g handles
// p = p0 + pass*16 + g. Lane t owns RBF center t and output chunk 4t..4t+3.

#define PP 2048
#define KK 16
#define NC 16
#define SFDIM 64
#define OUTF 64
#define THREADS 256
#define P_PER_BLOCK 64

__global__ __launch_bounds__(THREADS)
void rbfn_fused_kernel(const float* __restrict__ features,
                       const float4* __restrict__ spatial,   // (B,P,K,SFD) as float4
                       const float* __restrict__ centers,
                       const float* __restrict__ rbfw,
                       const float* __restrict__ w,
                       float4* __restrict__ out)              // (B,P,OUTF) as float4
{
    __shared__ float4 lds_w4[SFDIM * OUTF / 4];   // 16 KB: w[b] row-major (s, o)
    __shared__ float4 lds_wr4[NC * SFDIM / 4];    // 4 KB:  rbfw (c, s)

    const int tid = threadIdx.x;
    const int b = blockIdx.y;
    const int p0 = blockIdx.x * P_PER_BLOCK;

    const float4* wg4 = (const float4*)(w + (size_t)b * SFDIM * OUTF);
    #pragma unroll
    for (int i = 0; i < 4; ++i)
        lds_w4[tid + i * THREADS] = wg4[tid + i * THREADS];
    lds_wr4[tid] = ((const float4*)rbfw)[tid];
    __syncthreads();

    const int t = tid & 15;        // o4-chunk index / rbf-center index
    const int base = tid & 48;     // 16-lane group base within the wave

    const float C0 = centers[t];
    const float C1 = centers[NC + t];
    const float C2 = centers[2 * NC + t];

    // bp for pass i is bp0 + i*16; spatial row is 256 float4.
    const size_t bp0 = (size_t)b * PP + p0 + (tid >> 4);
    const float4* sp4 = spatial + bp0 * (KK * SFDIM / 4) + t;

    // ---- Phase A: all 4 passes' spatial k-reductions, one load stream ----
    // Per pass: 4 chains over k (k%4), final (a0+a1)+(a2+a3) — identical
    // summation tree to R6/R0-kernel1. 64 loads issued densely (16 loads per
    // k-quad across the 4 passes) so VMEM stays saturated.
    float4 a[4][4];   // [pass][chain] — fully unrolled, static indices only
    #pragma unroll
    for (int i = 0; i < 4; ++i)
        #pragma unroll
        for (int c = 0; c < 4; ++c)
            a[i][c] = sp4[(size_t)i * 4096 + c * 16];
    #pragma unroll
    for (int k = 4; k < KK; k += 4)
        #pragma unroll
        for (int i = 0; i < 4; ++i)
            #pragma unroll
            for (int c = 0; c < 4; ++c) {
                float4 v = sp4[(size_t)i * 4096 + (k + c) * 16];
                a[i][c].x += v.x; a[i][c].y += v.y;
                a[i][c].z += v.z; a[i][c].w += v.w;
            }

    float4 sp[4];
    #pragma unroll
    for (int i = 0; i < 4; ++i) {
        sp[i].x = (a[i][0].x + a[i][1].x) + (a[i][2].x + a[i][3].x);
        sp[i].y = (a[i][0].y + a[i][1].y) + (a[i][2].y + a[i][3].y);
        sp[i].z = (a[i][0].z + a[i][1].z) + (a[i][2].z + a[i][3].z);
        sp[i].w = (a[i][0].w + a[i][1].w) + (a[i][2].w + a[i][3].w);
    }

    // Keep tail loads out of Phase A's scheduling region.
    __builtin_amdgcn_sched_barrier(0);

    // ---- Phase B: per-pass compute tails (features/rbf/fl/o4/store) ------
    #pragma unroll
    for (int i = 0; i < 4; ++i) {
        const size_t bp = bp0 + (size_t)i * 16;

        // RBF sum for this lane's center c = t (identical math to R6)
        const float4* f4 = (const float4*)features + bp * 12;
        float rbfsum = 0.f;
        #define RBF_STEP(FX,FY,FZ) { \
            float dx=(FX)-C0, dy=(FY)-C1, dz=(FZ)-C2; \
            float dn2 = dx*dx + dy*dy + dz*dz; \
            rbfsum += __expf(dn2 * -12.5f); }
        #pragma unroll
        for (int kq = 0; kq < 4; ++kq) {
            float4 fa = f4[kq * 3 + 0];
            float4 fb = f4[kq * 3 + 1];
            float4 fc = f4[kq * 3 + 2];
            RBF_STEP(fa.x, fa.y, fa.z);
            RBF_STEP(fa.w, fb.x, fb.y);
            RBF_STEP(fb.z, fb.w, fc.x);
            RBF_STEP(fc.y, fc.z, fc.w);
        }
        #undef RBF_STEP

        // fl4 = sum_c rbfsum[c] * Wr[c, 4t..4t+3]
        float4 fl; fl.x = fl.y = fl.z = fl.w = 0.f;
        #pragma unroll
        for (int c = 0; c < NC; ++c) {
            float rs = __shfl(rbfsum, base | c, 64);
            float4 wr = lds_wr4[c * 16 + t];
            fl.x += rs * wr.x; fl.y += rs * wr.y;
            fl.z += rs * wr.z; fl.w += rs * wr.w;
        }

        // x = fl * sp[i]
        float4 x;
        x.x = fl.x * sp[i].x; x.y = fl.y * sp[i].y;
        x.z = fl.z * sp[i].z; x.w = fl.w * sp[i].w;

        // o4 = sum_s x[s] * w[b, s, 4t..4t+3]
        float4 o4; o4.x = o4.y = o4.z = o4.w = 0.f;
        #pragma unroll
        for (int sc = 0; sc < 16; ++sc) {
            float xs0 = __shfl(x.x, base | sc, 64);
            float xs1 = __shfl(x.y, base | sc, 64);
            float xs2 = __shfl(x.z, base | sc, 64);
            float xs3 = __shfl(x.w, base | sc, 64);
            float4 w0 = lds_w4[(sc * 4 + 0) * 16 + t];
            float4 w1 = lds_w4[(sc * 4 + 1) * 16 + t];
            float4 w2 = lds_w4[(sc * 4 + 2) * 16 + t];
            float4 w3 = lds_w4[(sc * 4 + 3) * 16 + t];
            o4.x += xs0 * w0.x + xs1 * w1.x + xs2 * w2.x + xs3 * w3.x;
            o4.y += xs0 * w0.y + xs1 * w1.y + xs2 * w2.y + xs3 * w3.y;
            o4.z += xs0 * w0.z + xs1 * w1.z + xs2 * w2.z + xs3 * w3.z;
            o4.w += xs0 * w0.w + xs1 * w1.w + xs2 * w2.w + xs3 * w3.w;
        }

        out[bp * 16 + t] = o4;

        // Cap register pressure: don't hoist pass i+1's 12 feature loads
        // above this point (R3 spilled from exactly that).
        __builtin_amdgcn_sched_barrier(0);
    }
}

extern "C" void kernel_launch(void* const* d_in, const int* in_sizes, int n_in,
                              void* d_out, int out_size, void* d_ws, size_t ws_size,
                              hipStream_t stream) {
    const float* features = (const float*)d_in[0];
    const float* spatial  = (const float*)d_in[1];
    const float* centers  = (const float*)d_in[2];
    const float* rbfw     = (const float*)d_in[3];
    const float* w        = (const float*)d_in[4];

    dim3 grid(PP / P_PER_BLOCK, 64);
    rbfn_fused_kernel<<<grid, THREADS, 0, stream>>>(
        features, (const float4*)spatial, centers, rbfw, w, (float4*)d_out);
}